// Round 7
// baseline (234.122 us; speedup 1.0000x reference)
//
#include <hip/hip_runtime.h>
#include <hip/hip_bf16.h>

#define N_NODES 50000
#define N_EDGES 819200
#define NUM_RELS 8
#define EPR (N_EDGES / NUM_RELS) /* 102400 */
#define N_HEADS 4
#define IN_FEAT 256
#define OUT_FEAT 128
#define HEAD_DIM 32
#define NB_SCAN ((N_NODES + 255) / 256) /* 196 */

typedef __attribute__((ext_vector_type(8))) __bf16 bf16x8;
typedef __attribute__((ext_vector_type(4))) __bf16 bf16x4;
typedef __attribute__((ext_vector_type(4))) float f32x4;

// ---- workspace layout (float units) ----
#define SZ_FEAT ((size_t)NUM_RELS * N_NODES * OUT_FEAT) /* 51.2M floats region */
#define SZ_EL ((size_t)NUM_RELS * N_NODES * N_HEADS)
#define SZ_WB ((size_t)IN_FEAT * 64) /* 16384 floats: wbt (8192) + wbl (8192) */
#define SZ_WT ((size_t)NUM_RELS * OUT_FEAT * IN_FEAT / 2) /* 131072 floats = 512KB */
#define OFF_FEAT ((size_t)0)
#define OFF_XB (OFF_FEAT + SZ_FEAT / 2) /* xb: 12.8M floats (25.6MB bf16), inside feat region */
#define OFF_EL (OFF_FEAT + SZ_FEAT)
#define OFF_ER (OFF_EL + SZ_EL)
#define OFF_WB (OFF_ER + SZ_EL)
#define OFF_WT (OFF_WB + SZ_WB)
#define OFF_INT (OFF_WT + SZ_WT)
#define IOFF_CNT ((size_t)0)
#define IOFF_PTR ((size_t)N_NODES)
#define IOFF_CUR ((size_t)2 * N_NODES)
#define IOFF_BSUM ((size_t)3 * N_NODES)
#define IOFF_SPAY ((size_t)3 * N_NODES + 256)

__device__ __forceinline__ void gload16(const void* g, void* l) {
    __builtin_amdgcn_global_load_lds(
        (const __attribute__((address_space(1))) unsigned int*)g,
        (__attribute__((address_space(3))) unsigned int*)l, 16, 0, 0);
}

// X -> bf16, pre-swizzled A image: row 512B = 32 x 16B slots; k-octet sg stored at
// slot (sg&~7)|((sg&7)^(n&7))  (inverse of the in-kernel read swizzle)
__global__ void k_cvtx(const float* __restrict__ x, __bf16* __restrict__ xb) {
    int tid = blockIdx.x * blockDim.x + threadIdx.x;
    if (tid >= N_NODES * 32) return;
    int n = tid >> 5, sg = tid & 31;
    const float* xp = x + (size_t)n * IN_FEAT + sg * 8;
    float4 a = *(const float4*)xp;
    float4 b = *(const float4*)(xp + 4);
    bf16x8 v;
    v[0] = (__bf16)a.x; v[1] = (__bf16)a.y; v[2] = (__bf16)a.z; v[3] = (__bf16)a.w;
    v[4] = (__bf16)b.x; v[5] = (__bf16)b.y; v[6] = (__bf16)b.z; v[7] = (__bf16)b.w;
    int slot = (sg & ~7) | ((sg & 7) ^ (n & 7));
    *(bf16x8*)(xb + (size_t)n * 256 + slot * 8) = v;
}

// weights -> per-(r,kc,ks) 8KB LDS images: [128 brow][4 slots of 16B],
// slot s holds k-octet q = s ^ ((brow>>1)&3); k = kc*64+ks*32+q*8
__global__ void k_cvtw(const float* __restrict__ cw, __bf16* __restrict__ wtl) {
    int tid = blockIdx.x * blockDim.x + threadIdx.x;
    if (tid >= 32768) return;
    int s = tid & 3, brow = (tid >> 2) & 127, ks = (tid >> 9) & 1, kc = (tid >> 10) & 3, r = tid >> 12;
    int q = s ^ ((brow >> 1) & 3);
    int k0 = kc * 64 + ks * 32 + q * 8;
    int h = brow >> 5, d = brow & 31;
    const float* src = cw + ((size_t)(r * N_HEADS + h) * IN_FEAT + k0) * HEAD_DIM + d;
    bf16x8 v;
#pragma unroll
    for (int j = 0; j < 8; ++j) v[j] = (__bf16)src[j * HEAD_DIM];
    *(bf16x8*)(wtl + (size_t)tid * 8) = v;
}

// folded attention vectors, transposed bf16: wbt[col][k], col = side*32+r*4+h
__global__ void k_wboth(const float* __restrict__ cw, const float* __restrict__ al,
                        const float* __restrict__ ar, __bf16* __restrict__ wbt) {
    int tid = blockIdx.x * blockDim.x + threadIdx.x;
    if (tid >= IN_FEAT * 64) return;
    int col = tid >> 8, i = tid & 255;
    int side = col >> 5, r = (col >> 2) & 7, h = col & 3;
    const float* av = (side ? ar : al) + (size_t)(r * N_HEADS + h) * HEAD_DIM;
    const float* cwp = cw + ((size_t)(r * N_HEADS + h) * IN_FEAT + i) * HEAD_DIM;
    float s = 0.f;
#pragma unroll
    for (int d = 0; d < HEAD_DIM; ++d) s += cwp[d] * av[d];
    wbt[(size_t)col * IN_FEAT + i] = (__bf16)s;
}

// wbt -> per-(kc,ks) 4KB images: [64 brow][4 slots], q = s ^ ((brow>>1)&3)
__global__ void k_wbimg(const __bf16* __restrict__ wbt, __bf16* __restrict__ wbl) {
    int tid = blockIdx.x * blockDim.x + threadIdx.x;
    if (tid >= 2048) return;
    int s = tid & 3, brow = (tid >> 2) & 63, ks = (tid >> 8) & 1, kc = tid >> 9;
    int q = s ^ ((brow >> 1) & 3);
    int k0 = kc * 64 + ks * 32 + q * 8;
    bf16x8 v = *(const bf16x8*)(wbt + (size_t)brow * IN_FEAT + k0);
    *(bf16x8*)(wbl + (size_t)tid * 8) = v;
}

// Fused transform: A staged once via global_load_lds (pre-swizzled xb), then
// 64 GEMM items (r,kc,ks) + 8 el/er items, double-buffered B with counted vmcnt.
__global__ __launch_bounds__(256, 2) void k_fused(const __bf16* __restrict__ xb,
                                                  const __bf16* __restrict__ wtl,
                                                  const __bf16* __restrict__ wbl,
                                                  __bf16* __restrict__ featb,
                                                  float* __restrict__ el,
                                                  float* __restrict__ er) {
    __shared__ __align__(16) unsigned char sA[65536]; // [128 rows][512B] swizzled
    __shared__ __align__(16) unsigned char sB[16384]; // 2 x 8KB chunk buffers
    const int t = threadIdx.x, lane = t & 63, w = t >> 6;
    const int wr = w >> 1, wc = w & 1;
    const int n0 = blockIdx.x * 128;

    // ---- prologue: issue A image (16 loads) + chunk 0 (2 loads) ----
#pragma unroll
    for (int i = 0; i < 16; ++i) {
        int off = i * 4096 + w * 1024 + lane * 16; // byte within tile image
        int row = off >> 9;
        int n = n0 + row;
        if (n >= N_NODES) n = N_NODES - 1;
        gload16((const char*)xb + (size_t)n * 512 + (off & 511), sA + i * 4096 + w * 1024);
    }
#pragma unroll
    for (int i = 0; i < 2; ++i)
        gload16((const char*)wtl + i * 4096 + w * 1024 + lane * 16, sB + i * 4096 + w * 1024);

    f32x4 acc[4][4];
#pragma unroll
    for (int i = 0; i < 4; ++i)
#pragma unroll
        for (int j = 0; j < 4; ++j) acc[i][j] = (f32x4){0.f, 0.f, 0.f, 0.f};

    // ---- 64 GEMM items ----
    for (int item = 0; item < 64; ++item) {
        const int buf = item & 1;
        if (item < 63) {
            const char* ch = (const char*)wtl + (size_t)(item + 1) * 8192;
#pragma unroll
            for (int i = 0; i < 2; ++i)
                gload16(ch + i * 4096 + w * 1024 + lane * 16, sB + (buf ^ 1) * 8192 + i * 4096 + w * 1024);
            asm volatile("s_waitcnt vmcnt(2)" ::: "memory");
        } else {
            gload16((const char*)wbl + w * 1024 + lane * 16, sB + (buf ^ 1) * 8192 + w * 1024);
            asm volatile("s_waitcnt vmcnt(1)" ::: "memory");
        }
        __builtin_amdgcn_s_barrier();
        __builtin_amdgcn_sched_barrier(0);

        const int r = item >> 3, kc = (item >> 1) & 3, ks = item & 1;
        bf16x8 af[4], bg[4];
#pragma unroll
        for (int rb = 0; rb < 4; ++rb) {
            int row = wr * 64 + rb * 16 + (lane & 15);
            int slot = kc * 8 + ((ks * 4 + (lane >> 4)) ^ (row & 7));
            af[rb] = *(const bf16x8*)(sA + row * 512 + slot * 16);
        }
#pragma unroll
        for (int cb = 0; cb < 4; ++cb) {
            int brow = wc * 64 + cb * 16 + (lane & 15);
            int s = (lane >> 4) ^ ((brow >> 1) & 3);
            bg[cb] = *(const bf16x8*)(sB + buf * 8192 + brow * 64 + s * 16);
        }
#pragma unroll
        for (int rb = 0; rb < 4; ++rb)
#pragma unroll
            for (int cb = 0; cb < 4; ++cb)
                acc[rb][cb] = __builtin_amdgcn_mfma_f32_16x16x32_bf16(af[rb], bg[cb], acc[rb][cb], 0, 0, 0);

        if ((item & 7) == 7) { // epilogue for rel r; C map col=lane&15, row=(lane>>4)*4+q
#pragma unroll
            for (int rb = 0; rb < 4; ++rb)
#pragma unroll
                for (int q = 0; q < 4; ++q) {
                    int rowi = wr * 64 + rb * 16 + (lane >> 4) * 4 + q;
                    int n = n0 + rowi;
                    if (n < N_NODES) {
                        __bf16* fp = featb + ((size_t)r * N_NODES + n) * OUT_FEAT + wc * 64 + (lane & 15);
#pragma unroll
                        for (int cb = 0; cb < 4; ++cb) fp[cb * 16] = (__bf16)acc[rb][cb][q];
                    }
                }
#pragma unroll
            for (int i = 0; i < 4; ++i)
#pragma unroll
                for (int j = 0; j < 4; ++j) acc[i][j] = (f32x4){0.f, 0.f, 0.f, 0.f};
        }
        asm volatile("" ::: "memory");
        __builtin_amdgcn_s_barrier();
    }

    // ---- 8 el/er items ----
    f32x4 acc2[4][2];
#pragma unroll
    for (int i = 0; i < 4; ++i)
#pragma unroll
        for (int j = 0; j < 2; ++j) acc2[i][j] = (f32x4){0.f, 0.f, 0.f, 0.f};

    for (int e = 0; e < 8; ++e) {
        const int buf = e & 1;
        if (e < 7) {
            gload16((const char*)wbl + (size_t)(e + 1) * 4096 + w * 1024 + lane * 16,
                    sB + (buf ^ 1) * 8192 + w * 1024);
            asm volatile("s_waitcnt vmcnt(1)" ::: "memory");
        } else {
            asm volatile("s_waitcnt vmcnt(0)" ::: "memory");
        }
        __builtin_amdgcn_s_barrier();
        __builtin_amdgcn_sched_barrier(0);

        const int kc = e >> 1, ks = e & 1;
        bf16x8 af[4], bg[2];
#pragma unroll
        for (int rb = 0; rb < 4; ++rb) {
            int row = wr * 64 + rb * 16 + (lane & 15);
            int slot = kc * 8 + ((ks * 4 + (lane >> 4)) ^ (row & 7));
            af[rb] = *(const bf16x8*)(sA + row * 512 + slot * 16);
        }
#pragma unroll
        for (int cb = 0; cb < 2; ++cb) {
            int brow = wc * 32 + cb * 16 + (lane & 15);
            int s = (lane >> 4) ^ ((brow >> 1) & 3);
            bg[cb] = *(const bf16x8*)(sB + buf * 8192 + brow * 64 + s * 16);
        }
#pragma unroll
        for (int rb = 0; rb < 4; ++rb)
#pragma unroll
            for (int cb = 0; cb < 2; ++cb)
                acc2[rb][cb] = __builtin_amdgcn_mfma_f32_16x16x32_bf16(af[rb], bg[cb], acc2[rb][cb], 0, 0, 0);
        asm volatile("" ::: "memory");
        __builtin_amdgcn_s_barrier();
    }
    // el/er epilogue
#pragma unroll
    for (int rb = 0; rb < 4; ++rb)
#pragma unroll
        for (int q = 0; q < 4; ++q) {
            int n = n0 + wr * 64 + rb * 16 + (lane >> 4) * 4 + q;
            if (n < N_NODES) {
#pragma unroll
                for (int cb = 0; cb < 2; ++cb) {
                    int c = wc * 32 + cb * 16 + (lane & 15);
                    int side = c >> 5, rr = (c >> 2) & 7, h = c & 3;
                    float* dst = side ? er : el;
                    dst[((size_t)rr * N_NODES + n) * N_HEADS + h] = acc2[rb][cb][q];
                }
            }
        }
}

// ---- CSR build ----
__global__ void k_hist(const int* __restrict__ col, int* __restrict__ cnt) {
    int e = blockIdx.x * blockDim.x + threadIdx.x;
    if (e < N_EDGES) atomicAdd(cnt + col[e], 1);
}

__global__ __launch_bounds__(256) void k_scanA(const int* __restrict__ cnt,
                                               int* __restrict__ excl,
                                               int* __restrict__ bsum) {
    __shared__ int s[256];
    int i = blockIdx.x * 256 + threadIdx.x;
    int v = (i < N_NODES) ? cnt[i] : 0;
    s[threadIdx.x] = v;
    __syncthreads();
#pragma unroll
    for (int off = 1; off < 256; off <<= 1) {
        int t = (threadIdx.x >= off) ? s[threadIdx.x - off] : 0;
        __syncthreads();
        s[threadIdx.x] += t;
        __syncthreads();
    }
    if (i < N_NODES) excl[i] = s[threadIdx.x] - v;
    if (threadIdx.x == 255) bsum[blockIdx.x] = s[255];
}

__global__ __launch_bounds__(256) void k_scanB(int* __restrict__ bsum) {
    __shared__ int s[256];
    int v = (threadIdx.x < NB_SCAN) ? bsum[threadIdx.x] : 0;
    s[threadIdx.x] = v;
    __syncthreads();
#pragma unroll
    for (int off = 1; off < 256; off <<= 1) {
        int t = (threadIdx.x >= off) ? s[threadIdx.x - off] : 0;
        __syncthreads();
        s[threadIdx.x] += t;
        __syncthreads();
    }
    bsum[threadIdx.x] = s[threadIdx.x] - v;
}

__global__ __launch_bounds__(256) void k_scanC(int* __restrict__ ptr,
                                               int* __restrict__ cursor,
                                               const int* __restrict__ bsum) {
    int i = blockIdx.x * 256 + threadIdx.x;
    if (i >= N_NODES) return;
    int p = ptr[i] + bsum[blockIdx.x];
    ptr[i] = p;
    cursor[i] = p;
}

__global__ void k_scatter(const int* __restrict__ row, const int* __restrict__ col,
                          int* __restrict__ cursor, int* __restrict__ spay) {
    int e = blockIdx.x * blockDim.x + threadIdx.x;
    if (e >= N_EDGES) return;
    int c = col[e];
    int pos = atomicAdd(cursor + c, 1);
    spay[pos] = row[e] | ((e / EPR) << 20);
}

// pull-aggregation, bf16 feat gather, 4-deep explicit pipeline
__global__ __launch_bounds__(256) void k_agg(const int* __restrict__ ptr,
                                             const int* __restrict__ cnt,
                                             const int* __restrict__ spay,
                                             const float* __restrict__ el,
                                             const float* __restrict__ er,
                                             const __bf16* __restrict__ featb,
                                             const float* __restrict__ bias,
                                             float* __restrict__ out) {
    const int wv = threadIdx.x >> 6, lane = threadIdx.x & 63;
    const int n = blockIdx.x * 4 + wv;
    if (n >= N_NODES) return;
    const int start = ptr[n], len = cnt[n];
    const int h = lane >> 4;
    float accx = 0.f, accy = 0.f, den = 0.f;
    int j = 0;
    for (; j + 4 <= len; j += 4) {
        int p[4];
#pragma unroll
        for (int u = 0; u < 4; ++u) p[u] = spay[start + j + u];
        float w[4], vx[4], vy[4];
#pragma unroll
        for (int u = 0; u < 4; ++u) {
            int rw = p[u] & 0xFFFFF, r = p[u] >> 20;
            size_t rb = (size_t)r * N_NODES;
            float s = el[(rb + rw) * N_HEADS + h] + er[(rb + n) * N_HEADS + h];
            s = s > 0.f ? s : 0.2f * s;
            w[u] = __expf(s);
            ushort2 raw = *(const ushort2*)(featb + (rb + rw) * OUT_FEAT + lane * 2);
            vx[u] = __uint_as_float((unsigned)raw.x << 16);
            vy[u] = __uint_as_float((unsigned)raw.y << 16);
        }
#pragma unroll
        for (int u = 0; u < 4; ++u) {
            accx += w[u] * vx[u];
            accy += w[u] * vy[u];
            den += w[u];
        }
    }
    for (; j < len; ++j) {
        int p = spay[start + j];
        int rw = p & 0xFFFFF, r = p >> 20;
        size_t rb = (size_t)r * N_NODES;
        float s = el[(rb + rw) * N_HEADS + h] + er[(rb + n) * N_HEADS + h];
        s = s > 0.f ? s : 0.2f * s;
        float w = __expf(s);
        ushort2 raw = *(const ushort2*)(featb + (rb + rw) * OUT_FEAT + lane * 2);
        accx += w * __uint_as_float((unsigned)raw.x << 16);
        accy += w * __uint_as_float((unsigned)raw.y << 16);
        den += w;
    }
    float inv = (len > 0) ? 1.f / den : 0.f;
    int o = lane * 2;
    float2 res;
    res.x = accx * inv + bias[o];
    res.y = accy * inv + bias[o + 1];
    *(float2*)(out + (size_t)n * OUT_FEAT + o) = res;
}

extern "C" void kernel_launch(void* const* d_in, const int* in_sizes, int n_in,
                              void* d_out, int out_size, void* d_ws, size_t ws_size,
                              hipStream_t stream) {
    const float* x = (const float*)d_in[0];
    const float* cw = (const float*)d_in[1];
    const float* al = (const float*)d_in[2];
    const float* ar = (const float*)d_in[3];
    const float* bias = (const float*)d_in[4];
    const int* row = (const int*)d_in[5];
    const int* col = (const int*)d_in[6];
    float* out = (float*)d_out;
    float* ws = (float*)d_ws;

    __bf16* featb = (__bf16*)(ws + OFF_FEAT);
    __bf16* xb = (__bf16*)(ws + OFF_XB);
    float* el = ws + OFF_EL;
    float* er = ws + OFF_ER;
    __bf16* wbt = (__bf16*)(ws + OFF_WB);
    __bf16* wbl = (__bf16*)(ws + OFF_WB + 8192);
    __bf16* wtl = (__bf16*)(ws + OFF_WT);
    int* iw = (int*)(ws + OFF_INT);
    int* cnt = iw + IOFF_CNT;
    int* ptr = iw + IOFF_PTR;
    int* cur = iw + IOFF_CUR;
    int* bsum = iw + IOFF_BSUM;
    int* spay = iw + IOFF_SPAY;

    hipMemsetAsync(cnt, 0, N_NODES * sizeof(int), stream);

    k_cvtx<<<(N_NODES * 32 + 255) / 256, 256, 0, stream>>>(x, xb);
    k_cvtw<<<128, 256, 0, stream>>>(cw, wtl);
    k_wboth<<<(IN_FEAT * 64 + 255) / 256, 256, 0, stream>>>(cw, al, ar, wbt);
    k_wbimg<<<8, 256, 0, stream>>>(wbt, wbl);
    k_fused<<<(N_NODES + 127) / 128, 256, 0, stream>>>(xb, wtl, wbl, featb, el, er);

    k_hist<<<(N_EDGES + 255) / 256, 256, 0, stream>>>(col, cnt);
    k_scanA<<<NB_SCAN, 256, 0, stream>>>(cnt, ptr, bsum);
    k_scanB<<<1, 256, 0, stream>>>(bsum);
    k_scanC<<<NB_SCAN, 256, 0, stream>>>(ptr, cur, bsum);
    k_scatter<<<(N_EDGES + 255) / 256, 256, 0, stream>>>(row, col, cur, spay);

    k_agg<<<(N_NODES + 3) / 4, 256, 0, stream>>>(ptr, cnt, spay, el, er, featb, bias, out);
}